// Round 9
// baseline (175.119 us; speedup 1.0000x reference)
//
#include <hip/hip_runtime.h>

#define N_DRUG 20000
#define N_PROT 8000
#define D_DRUG 300
#define D_PROT 1280
#define HIDDEN 512
#define OUT_D  5
#define N_EDGE 500000
#define N_LBL  200000
#define WLD    812        // W_lin leading dim (300+512)
#define CAP    128        // bucket capacity (deg ~ 62.5 +- 7.9; ~8 sigma)
#define OVF_MAX 65536     // exact overflow list (never expected to fill)
#define SBLK   1954       // scatter blocks in D2: 1 edge/thread -> max atomic MLP

// =========================================================================
// D1: folded weights (h-split 8x, atomic partials onto zeroed A/B/c)
//   A[o,k] = sum_h W_lin[o,300+h] * W_l[h,k]   (5 x 300)
//   B[o,k] = sum_h W_lin[o,300+h] * W_r[h,k]   (5 x 1280)
//   c[o]   = sum_h W_lin[o,300+h] * b_l[h]     (5)
// =========================================================================
__global__ void k_fold(const float* __restrict__ W_l, const float* __restrict__ W_r,
                       const float* __restrict__ W_lin, const float* __restrict__ b_l,
                       float* __restrict__ A, float* __restrict__ B, float* __restrict__ c) {
    int t  = (blockIdx.x % 31) * 256 + threadIdx.x;
    int h0 = (blockIdx.x / 31) * 64;
    const int nA = OUT_D * D_DRUG;   // 1500
    const int nB = OUT_D * D_PROT;   // 6400
    if (t < nA) {
        int o = t / D_DRUG, k = t - o * D_DRUG;
        const float* wp = W_lin + o * WLD + D_DRUG + h0;
        const float* wl = W_l + (size_t)h0 * D_DRUG + k;
        float s = 0.f;
#pragma unroll 4
        for (int h = 0; h < 64; ++h) s += wp[h] * wl[h * D_DRUG];
        atomicAdd(&A[t], s);
    } else if (t < nA + nB) {
        int u = t - nA;
        int o = u / D_PROT, k = u - o * D_PROT;
        const float* wp = W_lin + o * WLD + D_DRUG + h0;
        const float* wr = W_r + (size_t)h0 * D_PROT + k;
        float s = 0.f;
#pragma unroll 4
        for (int h = 0; h < 64; ++h) s += wp[h] * wr[h * D_PROT];
        atomicAdd(&B[u], s);
    } else if (t < nA + nB + OUT_D) {
        int o = t - nA - nB;
        const float* wp = W_lin + o * WLD + D_DRUG + h0;
        float s = 0.f;
        for (int h = 0; h < 64; ++h) s += wp[h] * b_l[h0 + h];
        atomicAdd(&c[o], s);
    }
}

// =========================================================================
// D2: scatter || both dense GEMMs, block-specialized.
//   blocks [0,1954):     bucketed edge scatter, 1 edge/thread (max MLP —
//                        round-8's 128-block grid-stride version serialized
//                        ~15 dependent atomic round-trips per thread: 48us)
//   blocks [1954,3204):  drug rows: P_A = x_drug@A.T, drugO = x_drug@Wlin_d.T
//   blocks [3204,5204):  prot rows: protO = x_prot@B.T + c
// Scatter blocks dispatch first and own the atomic pipe; the HBM-bound GEMM
// stream hides under the ~20-25us atomic wall.
// =========================================================================
__global__ void k_mid(const float* __restrict__ x_drug, const float* __restrict__ x_prot,
                      const int* __restrict__ edge_src, const int* __restrict__ edge_dst,
                      const float* __restrict__ A, const float* __restrict__ B,
                      const float* __restrict__ c, const float* __restrict__ W_lin,
                      int* __restrict__ cnt, int* __restrict__ novf,
                      int* __restrict__ bucket, int* __restrict__ ovf,
                      float* __restrict__ P_A, float* __restrict__ drugO,
                      float* __restrict__ protO) {
    int b = blockIdx.x;
    int tid = threadIdx.x;
    if (b < SBLK) {
        // ---- bucketed scatter: r = cnt[d]++; bucket[d*CAP+r] = s ----
        int e = b * 256 + tid;
        if (e < N_EDGE) {
            int s = edge_src[e], d = edge_dst[e];
            int r = atomicAdd(&cnt[d], 1);
            if (r < CAP) {
                bucket[d * CAP + r] = s;
            } else {    // exact overflow list (input-only fallback)
                int o = atomicAdd(novf, 1);
                if (o < OVF_MAX) { ovf[2 * o] = d; ovf[2 * o + 1] = s; }
            }
        }
    } else if (b < SBLK + 1250) {
        // ---- drug rows: 16 rows/block x 16 lanes/row ----
        int row = (b - SBLK) * 16 + (tid >> 4);
        int sub = tid & 15;
        const float4* xr = (const float4*)(x_drug + (size_t)row * D_DRUG);  // 75 float4
        float acc[10];
#pragma unroll
        for (int i = 0; i < 10; ++i) acc[i] = 0.f;
        for (int k = sub; k < D_DRUG / 4; k += 16) {
            float4 x = xr[k];
#pragma unroll
            for (int o = 0; o < OUT_D; ++o) {
                float4 a = ((const float4*)(A + o * D_DRUG))[k];
                acc[o] += x.x * a.x + x.y * a.y + x.z * a.z + x.w * a.w;
                float4 w = ((const float4*)(W_lin + o * WLD))[k];
                acc[5 + o] += x.x * w.x + x.y * w.y + x.z * w.z + x.w * w.w;
            }
        }
#pragma unroll
        for (int i = 0; i < 10; ++i) {
            float v = acc[i];
            for (int m = 8; m; m >>= 1) v += __shfl_xor(v, m, 64);
            acc[i] = v;
        }
        if (sub < OUT_D) {
            P_A[row * OUT_D + sub]   = acc[sub];
            drugO[row * OUT_D + sub] = acc[5 + sub];
        }
    } else {
        // ---- prot rows: 4 rows/block x 64 lanes/row ----
        int row  = (b - SBLK - 1250) * 4 + (tid >> 6);
        int lane = tid & 63;
        const float4* xr = (const float4*)(x_prot + (size_t)row * D_PROT);  // 320 float4
        float acc[OUT_D] = {0.f, 0.f, 0.f, 0.f, 0.f};
        for (int k = lane; k < D_PROT / 4; k += 64) {
            float4 x = xr[k];
#pragma unroll
            for (int o = 0; o < OUT_D; ++o) {
                float4 bb = ((const float4*)(B + o * D_PROT))[k];
                acc[o] += x.x * bb.x + x.y * bb.y + x.z * bb.z + x.w * bb.w;
            }
        }
#pragma unroll
        for (int o = 0; o < OUT_D; ++o) {
            float v = acc[o];
            for (int off = 32; off; off >>= 1) v += __shfl_xor(v, off, 64);
            acc[o] = v;
        }
        if (lane < OUT_D) protO[row * OUT_D + lane] = acc[lane] + c[lane];
    }
}

// =========================================================================
// D3: bucket gather-mean, added into protO (one wave per protein)
// =========================================================================
__global__ void k_gather(const int* __restrict__ cnt, const int* __restrict__ novf,
                         const int* __restrict__ bucket, const int* __restrict__ ovf,
                         const float* __restrict__ P_A, float* __restrict__ protO) {
    int wave = (blockIdx.x * blockDim.x + threadIdx.x) >> 6;
    int lane = threadIdx.x & 63;
    if (wave >= N_PROT) return;
    int deg = cnt[wave];
    int m = deg < CAP ? deg : CAP;
    float acc[OUT_D] = {0.f, 0.f, 0.f, 0.f, 0.f};
    const int* br = &bucket[wave * CAP];
    for (int j = lane; j < m; j += 64) {
        const float* p = &P_A[br[j] * OUT_D];
#pragma unroll
        for (int o = 0; o < OUT_D; ++o) acc[o] += p[o];
    }
    if (deg > CAP) {   // exact tail via overflow list
        int nv = *novf; if (nv > OVF_MAX) nv = OVF_MAX;
        for (int j = lane; j < nv; j += 64) {
            if (ovf[2 * j] == wave) {
                const float* p = &P_A[ovf[2 * j + 1] * OUT_D];
#pragma unroll
                for (int o = 0; o < OUT_D; ++o) acc[o] += p[o];
            }
        }
    }
#pragma unroll
    for (int o = 0; o < OUT_D; ++o) {
        float v = acc[o];
        for (int off = 32; off; off >>= 1) v += __shfl_xor(v, off, 64);
        acc[o] = v;
    }
    if (lane < OUT_D)
        protO[wave * OUT_D + lane] += acc[lane] / fmaxf((float)deg, 1.f);
}

// =========================================================================
// D4: final gather-add
// =========================================================================
__global__ void k_final(const int* __restrict__ lbl_src, const int* __restrict__ lbl_dst,
                        const float* __restrict__ drugO, const float* __restrict__ protO,
                        const float* __restrict__ b_lin, float* __restrict__ out) {
    int l = blockIdx.x * blockDim.x + threadIdx.x;
    if (l >= N_LBL) return;
    int s = lbl_src[l], d = lbl_dst[l];
    const float* dr = &drugO[s * OUT_D];
    const float* pr = &protO[d * OUT_D];
    float* op = &out[(size_t)l * OUT_D];
    op[0] = dr[0] + pr[0] + b_lin[0];
    op[1] = dr[1] + pr[1] + b_lin[1];
    op[2] = dr[2] + pr[2] + b_lin[2];
    op[3] = dr[3] + pr[3] + b_lin[3];
    op[4] = dr[4] + pr[4] + b_lin[4];
}

extern "C" void kernel_launch(void* const* d_in, const int* in_sizes, int n_in,
                              void* d_out, int out_size, void* d_ws, size_t ws_size,
                              hipStream_t stream) {
    const float* x_drug   = (const float*)d_in[0];
    const float* x_prot   = (const float*)d_in[1];
    const int*   edge_src = (const int*)d_in[2];
    const int*   edge_dst = (const int*)d_in[3];
    const int*   lbl_src  = (const int*)d_in[4];
    const int*   lbl_dst  = (const int*)d_in[5];
    const float* W_l      = (const float*)d_in[6];
    const float* b_l      = (const float*)d_in[7];
    const float* W_r      = (const float*)d_in[8];
    const float* W_lin    = (const float*)d_in[9];
    const float* b_lin    = (const float*)d_in[10];
    float* out = (float*)d_out;

    // workspace layout; [0, 63648) zeroed by the single memset
    char* ws = (char*)d_ws;
    int*   cnt    = (int*)  (ws + 0);          //  32000 B (8000)     [zeroed]
    int*   novf   = (int*)  (ws + 32000);      //     16 B           [zeroed]
    float* A      = (float*)(ws + 32016);      //   6000 B (5x300)   [zeroed]
    float* B      = (float*)(ws + 38016);      //  25600 B (5x1280)  [zeroed]
    float* c      = (float*)(ws + 63616);      //     20 B           [zeroed]
    float* P_A    = (float*)(ws + 64000);      // 400000 B
    float* drugO  = (float*)(ws + 464000);     // 400000 B
    float* protO  = (float*)(ws + 864000);     // 160000 B
    int*   bucket = (int*)  (ws + 1024000);    // 4096000 B (8000 x 128)
    int*   ovf    = (int*)  (ws + 5120000);    // 524288 B (65536 pairs)
    // total: 5,644,288 B

    hipMemsetAsync(ws, 0, 63648, stream);
    k_fold<<<248, 256, 0, stream>>>(W_l, W_r, W_lin, b_l, A, B, c);
    k_mid<<<SBLK + 1250 + 2000, 256, 0, stream>>>(
        x_drug, x_prot, edge_src, edge_dst, A, B, c, W_lin,
        cnt, novf, bucket, ovf, P_A, drugO, protO);
    k_gather<<<(N_PROT * 64) / 256, 256, 0, stream>>>(cnt, novf, bucket, ovf, P_A, protO);
    k_final<<<(N_LBL + 255) / 256, 256, 0, stream>>>(lbl_src, lbl_dst, drugO, protO, b_lin, out);
}

// Round 10
// 173.851 us; speedup vs baseline: 1.0073x; 1.0073x over previous
//
#include <hip/hip_runtime.h>

#define N_DRUG 20000
#define N_PROT 8000
#define D_DRUG 300
#define D_PROT 1280
#define HIDDEN 512
#define OUT_D  5
#define N_EDGE 500000
#define N_LBL  200000
#define WLD    812        // W_lin leading dim (300+512)
#define CAP    96         // bucket capacity (E[max deg] ~ 95.6; exact ovf list catches tail)
#define CSTR   32         // cnt stride in ints: one counter per 128B line (kills hot-line RMW chains)
#define OVF_MAX 65536     // exact overflow list
#define SBLK   1954       // scatter blocks in D2: 1 edge/thread

// =========================================================================
// D1: folded weights (h-split 8x, atomic partials onto zeroed A/B/c)
//   A[o,k] = sum_h W_lin[o,300+h] * W_l[h,k]   (5 x 300)
//   B[o,k] = sum_h W_lin[o,300+h] * W_r[h,k]   (5 x 1280)
//   c[o]   = sum_h W_lin[o,300+h] * b_l[h]     (5)
// =========================================================================
__global__ void k_fold(const float* __restrict__ W_l, const float* __restrict__ W_r,
                       const float* __restrict__ W_lin, const float* __restrict__ b_l,
                       float* __restrict__ A, float* __restrict__ B, float* __restrict__ c) {
    int t  = (blockIdx.x % 31) * 256 + threadIdx.x;
    int h0 = (blockIdx.x / 31) * 64;
    const int nA = OUT_D * D_DRUG;   // 1500
    const int nB = OUT_D * D_PROT;   // 6400
    if (t < nA) {
        int o = t / D_DRUG, k = t - o * D_DRUG;
        const float* wp = W_lin + o * WLD + D_DRUG + h0;
        const float* wl = W_l + (size_t)h0 * D_DRUG + k;
        float s = 0.f;
#pragma unroll 4
        for (int h = 0; h < 64; ++h) s += wp[h] * wl[h * D_DRUG];
        atomicAdd(&A[t], s);
    } else if (t < nA + nB) {
        int u = t - nA;
        int o = u / D_PROT, k = u - o * D_PROT;
        const float* wp = W_lin + o * WLD + D_DRUG + h0;
        const float* wr = W_r + (size_t)h0 * D_PROT + k;
        float s = 0.f;
#pragma unroll 4
        for (int h = 0; h < 64; ++h) s += wp[h] * wr[h * D_PROT];
        atomicAdd(&B[u], s);
    } else if (t < nA + nB + OUT_D) {
        int o = t - nA - nB;
        const float* wp = W_lin + o * WLD + D_DRUG + h0;
        float s = 0.f;
        for (int h = 0; h < 64; ++h) s += wp[h] * b_l[h0 + h];
        atomicAdd(&c[o], s);
    }
}

// =========================================================================
// D2: scatter || both dense GEMMs, block-specialized.
//   blocks [0,1954):     bucketed edge scatter, 1 edge/thread; cnt padded to
//                        1 counter / 128B line — round-8/9 showed the wall is
//                        memory-side same-line RMW serialization (16-32
//                        counters/line -> ~1000 serialized ops on hot lines)
//   blocks [1954,3204):  drug rows: P_A = x_drug@A.T, drugO = x_drug@Wlin_d.T
//   blocks [3204,5204):  prot rows: protO = x_prot@B.T + c
// =========================================================================
__global__ void k_mid(const float* __restrict__ x_drug, const float* __restrict__ x_prot,
                      const int* __restrict__ edge_src, const int* __restrict__ edge_dst,
                      const float* __restrict__ A, const float* __restrict__ B,
                      const float* __restrict__ c, const float* __restrict__ W_lin,
                      int* __restrict__ cnt, int* __restrict__ novf,
                      int* __restrict__ bucket, int* __restrict__ ovf,
                      float* __restrict__ P_A, float* __restrict__ drugO,
                      float* __restrict__ protO) {
    int b = blockIdx.x;
    int tid = threadIdx.x;
    if (b < SBLK) {
        // ---- bucketed scatter: r = cnt[d]++; bucket[d*CAP+r] = s ----
        int e = b * 256 + tid;
        if (e < N_EDGE) {
            int s = edge_src[e], d = edge_dst[e];
            int r = atomicAdd(&cnt[d * CSTR], 1);
            if (r < CAP) {
                bucket[d * CAP + r] = s;
            } else {    // exact overflow list (rarely hit; a few edges at most)
                int o = atomicAdd(novf, 1);
                if (o < OVF_MAX) { ovf[2 * o] = d; ovf[2 * o + 1] = s; }
            }
        }
    } else if (b < SBLK + 1250) {
        // ---- drug rows: 16 rows/block x 16 lanes/row ----
        int row = (b - SBLK) * 16 + (tid >> 4);
        int sub = tid & 15;
        const float4* xr = (const float4*)(x_drug + (size_t)row * D_DRUG);  // 75 float4
        float acc[10];
#pragma unroll
        for (int i = 0; i < 10; ++i) acc[i] = 0.f;
        for (int k = sub; k < D_DRUG / 4; k += 16) {
            float4 x = xr[k];
#pragma unroll
            for (int o = 0; o < OUT_D; ++o) {
                float4 a = ((const float4*)(A + o * D_DRUG))[k];
                acc[o] += x.x * a.x + x.y * a.y + x.z * a.z + x.w * a.w;
                float4 w = ((const float4*)(W_lin + o * WLD))[k];
                acc[5 + o] += x.x * w.x + x.y * w.y + x.z * w.z + x.w * w.w;
            }
        }
#pragma unroll
        for (int i = 0; i < 10; ++i) {
            float v = acc[i];
            for (int m = 8; m; m >>= 1) v += __shfl_xor(v, m, 64);
            acc[i] = v;
        }
        if (sub < OUT_D) {
            P_A[row * OUT_D + sub]   = acc[sub];
            drugO[row * OUT_D + sub] = acc[5 + sub];
        }
    } else {
        // ---- prot rows: 4 rows/block x 64 lanes/row ----
        int row  = (b - SBLK - 1250) * 4 + (tid >> 6);
        int lane = tid & 63;
        const float4* xr = (const float4*)(x_prot + (size_t)row * D_PROT);  // 320 float4
        float acc[OUT_D] = {0.f, 0.f, 0.f, 0.f, 0.f};
        for (int k = lane; k < D_PROT / 4; k += 64) {
            float4 x = xr[k];
#pragma unroll
            for (int o = 0; o < OUT_D; ++o) {
                float4 bb = ((const float4*)(B + o * D_PROT))[k];
                acc[o] += x.x * bb.x + x.y * bb.y + x.z * bb.z + x.w * bb.w;
            }
        }
#pragma unroll
        for (int o = 0; o < OUT_D; ++o) {
            float v = acc[o];
            for (int off = 32; off; off >>= 1) v += __shfl_xor(v, off, 64);
            acc[o] = v;
        }
        if (lane < OUT_D) protO[row * OUT_D + lane] = acc[lane] + c[lane];
    }
}

// =========================================================================
// D3: bucket gather-mean, added into protO (one wave per protein)
// =========================================================================
__global__ void k_gather(const int* __restrict__ cnt, const int* __restrict__ novf,
                         const int* __restrict__ bucket, const int* __restrict__ ovf,
                         const float* __restrict__ P_A, float* __restrict__ protO) {
    int wave = (blockIdx.x * blockDim.x + threadIdx.x) >> 6;
    int lane = threadIdx.x & 63;
    if (wave >= N_PROT) return;
    int deg = cnt[wave * CSTR];
    int m = deg < CAP ? deg : CAP;
    float acc[OUT_D] = {0.f, 0.f, 0.f, 0.f, 0.f};
    const int* br = &bucket[wave * CAP];
    for (int j = lane; j < m; j += 64) {
        const float* p = &P_A[br[j] * OUT_D];
#pragma unroll
        for (int o = 0; o < OUT_D; ++o) acc[o] += p[o];
    }
    if (deg > CAP) {   // exact tail via overflow list
        int nv = *novf; if (nv > OVF_MAX) nv = OVF_MAX;
        for (int j = lane; j < nv; j += 64) {
            if (ovf[2 * j] == wave) {
                const float* p = &P_A[ovf[2 * j + 1] * OUT_D];
#pragma unroll
                for (int o = 0; o < OUT_D; ++o) acc[o] += p[o];
            }
        }
    }
#pragma unroll
    for (int o = 0; o < OUT_D; ++o) {
        float v = acc[o];
        for (int off = 32; off; off >>= 1) v += __shfl_xor(v, off, 64);
        acc[o] = v;
    }
    if (lane < OUT_D)
        protO[wave * OUT_D + lane] += acc[lane] / fmaxf((float)deg, 1.f);
}

// =========================================================================
// D4: final gather-add
// =========================================================================
__global__ void k_final(const int* __restrict__ lbl_src, const int* __restrict__ lbl_dst,
                        const float* __restrict__ drugO, const float* __restrict__ protO,
                        const float* __restrict__ b_lin, float* __restrict__ out) {
    int l = blockIdx.x * blockDim.x + threadIdx.x;
    if (l >= N_LBL) return;
    int s = lbl_src[l], d = lbl_dst[l];
    const float* dr = &drugO[s * OUT_D];
    const float* pr = &protO[d * OUT_D];
    float* op = &out[(size_t)l * OUT_D];
    op[0] = dr[0] + pr[0] + b_lin[0];
    op[1] = dr[1] + pr[1] + b_lin[1];
    op[2] = dr[2] + pr[2] + b_lin[2];
    op[3] = dr[3] + pr[3] + b_lin[3];
    op[4] = dr[4] + pr[4] + b_lin[4];
}

extern "C" void kernel_launch(void* const* d_in, const int* in_sizes, int n_in,
                              void* d_out, int out_size, void* d_ws, size_t ws_size,
                              hipStream_t stream) {
    const float* x_drug   = (const float*)d_in[0];
    const float* x_prot   = (const float*)d_in[1];
    const int*   edge_src = (const int*)d_in[2];
    const int*   edge_dst = (const int*)d_in[3];
    const int*   lbl_src  = (const int*)d_in[4];
    const int*   lbl_dst  = (const int*)d_in[5];
    const float* W_l      = (const float*)d_in[6];
    const float* b_l      = (const float*)d_in[7];
    const float* W_r      = (const float*)d_in[8];
    const float* W_lin    = (const float*)d_in[9];
    const float* b_lin    = (const float*)d_in[10];
    float* out = (float*)d_out;

    // workspace layout; [0, 1055648) zeroed by the single memset
    char* ws = (char*)d_ws;
    int*   cnt    = (int*)  (ws + 0);          // 1024000 B (8000 x 128B-padded) [zeroed]
    int*   novf   = (int*)  (ws + 1024000);    //     16 B                      [zeroed]
    float* A      = (float*)(ws + 1024016);    //   6000 B (5x300)              [zeroed]
    float* B      = (float*)(ws + 1030016);    //  25600 B (5x1280)             [zeroed]
    float* c      = (float*)(ws + 1055616);    //     20 B                      [zeroed]
    float* P_A    = (float*)(ws + 1056000);    // 400000 B
    float* drugO  = (float*)(ws + 1456000);    // 400000 B
    float* protO  = (float*)(ws + 1856000);    // 160000 B
    int*   bucket = (int*)  (ws + 2016000);    // 3072000 B (8000 x 96)
    int*   ovf    = (int*)  (ws + 5088000);    // 524288 B (65536 pairs)
    // total: 5,612,288 B (same footprint class as round 9's 5.64 MB)

    hipMemsetAsync(ws, 0, 1055648, stream);
    k_fold<<<248, 256, 0, stream>>>(W_l, W_r, W_lin, b_l, A, B, c);
    k_mid<<<SBLK + 1250 + 2000, 256, 0, stream>>>(
        x_drug, x_prot, edge_src, edge_dst, A, B, c, W_lin,
        cnt, novf, bucket, ovf, P_A, drugO, protO);
    k_gather<<<(N_PROT * 64) / 256, 256, 0, stream>>>(cnt, novf, bucket, ovf, P_A, protO);
    k_final<<<(N_LBL + 255) / 256, 256, 0, stream>>>(lbl_src, lbl_dst, drugO, protO, b_lin, out);
}

// Round 11
// 173.187 us; speedup vs baseline: 1.0112x; 1.0038x over previous
//
#include <hip/hip_runtime.h>

#define N_DRUG 20000
#define N_PROT 8000
#define D_DRUG 300
#define D_PROT 1280
#define HIDDEN 512
#define OUT_D  5
#define N_EDGE 500000
#define N_LBL  200000
#define WLD    812        // W_lin leading dim (300+512)
#define CAP    96         // bucket capacity (E[max deg] ~95.6; exact ovf list catches tail)
#define OVF_MAX 65536     // exact overflow list
#define EPB    154        // edges per block: 3250*154 = 500500 >= 500000

// =========================================================================
// D1: folded weights (h-split 8x, atomic partials onto zeroed A/B/c)
//   A[o,k] = sum_h W_lin[o,300+h] * W_l[h,k]   (5 x 300)
//   B[o,k] = sum_h W_lin[o,300+h] * W_r[h,k]   (5 x 1280)
//   c[o]   = sum_h W_lin[o,300+h] * b_l[h]     (5)
// =========================================================================
__global__ void k_fold(const float* __restrict__ W_l, const float* __restrict__ W_r,
                       const float* __restrict__ W_lin, const float* __restrict__ b_l,
                       float* __restrict__ A, float* __restrict__ B, float* __restrict__ c) {
    int t  = (blockIdx.x % 31) * 256 + threadIdx.x;
    int h0 = (blockIdx.x / 31) * 64;
    const int nA = OUT_D * D_DRUG;   // 1500
    const int nB = OUT_D * D_PROT;   // 6400
    if (t < nA) {
        int o = t / D_DRUG, k = t - o * D_DRUG;
        const float* wp = W_lin + o * WLD + D_DRUG + h0;
        const float* wl = W_l + (size_t)h0 * D_DRUG + k;
        float s = 0.f;
#pragma unroll 4
        for (int h = 0; h < 64; ++h) s += wp[h] * wl[h * D_DRUG];
        atomicAdd(&A[t], s);
    } else if (t < nA + nB) {
        int u = t - nA;
        int o = u / D_PROT, k = u - o * D_PROT;
        const float* wp = W_lin + o * WLD + D_DRUG + h0;
        const float* wr = W_r + (size_t)h0 * D_PROT + k;
        float s = 0.f;
#pragma unroll 4
        for (int h = 0; h < 64; ++h) s += wp[h] * wr[h * D_PROT];
        atomicAdd(&B[u], s);
    } else if (t < nA + nB + OUT_D) {
        int o = t - nA - nB;
        const float* wp = W_lin + o * WLD + D_DRUG + h0;
        float s = 0.f;
        for (int h = 0; h < 64; ++h) s += wp[h] * b_l[h0 + h];
        atomicAdd(&c[o], s);
    }
}

// =========================================================================
// D2: scatter FUSED INTO every GEMM block (not block-partitioned roles:
// rounds 8-10 showed role-partitioned blocks phase-separate — scatter blocks
// fill the device first, drain their ~25us atomic wall, THEN GEMM runs:
// additive ~50us. Here each of the 3250 GEMM blocks first fires ~154 edge
// atomics (threads 0..153), then streams its GEMM: the device-scope RMW
// pipe and the HBM/VALU pipes overlap for the kernel's whole lifetime.)
//   blocks [0,1250):     drug rows: P_A = x_drug@A.T, drugO = x_drug@Wlin_d.T
//   blocks [1250,3250):  prot rows: protO = x_prot@B.T + c
// =========================================================================
__global__ void k_mid(const float* __restrict__ x_drug, const float* __restrict__ x_prot,
                      const int* __restrict__ edge_src, const int* __restrict__ edge_dst,
                      const float* __restrict__ A, const float* __restrict__ B,
                      const float* __restrict__ c, const float* __restrict__ W_lin,
                      int* __restrict__ cnt, int* __restrict__ novf,
                      int* __restrict__ bucket, int* __restrict__ ovf,
                      float* __restrict__ P_A, float* __restrict__ drugO,
                      float* __restrict__ protO) {
    int b = blockIdx.x;
    int tid = threadIdx.x;

    // ---- scatter prologue: this block's ~154 edges, 1 atomic/thread ----
    {
        int e = b * EPB + tid;
        if (tid < EPB && e < N_EDGE) {
            int s = edge_src[e], d = edge_dst[e];
            int r = atomicAdd(&cnt[d], 1);
            if (r < CAP) {
                bucket[d * CAP + r] = s;
            } else {    // exact overflow list (tail of max-degree distribution)
                int o = atomicAdd(novf, 1);
                if (o < OVF_MAX) { ovf[2 * o] = d; ovf[2 * o + 1] = s; }
            }
        }
    }

    // ---- GEMM body ----
    if (b < 1250) {
        // drug rows: 16 rows/block x 16 lanes/row
        int row = b * 16 + (tid >> 4);
        int sub = tid & 15;
        const float4* xr = (const float4*)(x_drug + (size_t)row * D_DRUG);  // 75 float4
        float acc[10];
#pragma unroll
        for (int i = 0; i < 10; ++i) acc[i] = 0.f;
        for (int k = sub; k < D_DRUG / 4; k += 16) {
            float4 x = xr[k];
#pragma unroll
            for (int o = 0; o < OUT_D; ++o) {
                float4 a = ((const float4*)(A + o * D_DRUG))[k];
                acc[o] += x.x * a.x + x.y * a.y + x.z * a.z + x.w * a.w;
                float4 w = ((const float4*)(W_lin + o * WLD))[k];
                acc[5 + o] += x.x * w.x + x.y * w.y + x.z * w.z + x.w * w.w;
            }
        }
#pragma unroll
        for (int i = 0; i < 10; ++i) {
            float v = acc[i];
            for (int m = 8; m; m >>= 1) v += __shfl_xor(v, m, 64);
            acc[i] = v;
        }
        if (sub < OUT_D) {
            P_A[row * OUT_D + sub]   = acc[sub];
            drugO[row * OUT_D + sub] = acc[5 + sub];
        }
    } else {
        // prot rows: 4 rows/block x 64 lanes/row
        int row  = (b - 1250) * 4 + (tid >> 6);
        int lane = tid & 63;
        const float4* xr = (const float4*)(x_prot + (size_t)row * D_PROT);  // 320 float4
        float acc[OUT_D] = {0.f, 0.f, 0.f, 0.f, 0.f};
        for (int k = lane; k < D_PROT / 4; k += 64) {
            float4 x = xr[k];
#pragma unroll
            for (int o = 0; o < OUT_D; ++o) {
                float4 bb = ((const float4*)(B + o * D_PROT))[k];
                acc[o] += x.x * bb.x + x.y * bb.y + x.z * bb.z + x.w * bb.w;
            }
        }
#pragma unroll
        for (int o = 0; o < OUT_D; ++o) {
            float v = acc[o];
            for (int off = 32; off; off >>= 1) v += __shfl_xor(v, off, 64);
            acc[o] = v;
        }
        if (lane < OUT_D) protO[row * OUT_D + lane] = acc[lane] + c[lane];
    }
}

// =========================================================================
// D3: bucket gather-mean, added into protO (one wave per protein)
// =========================================================================
__global__ void k_gather(const int* __restrict__ cnt, const int* __restrict__ novf,
                         const int* __restrict__ bucket, const int* __restrict__ ovf,
                         const float* __restrict__ P_A, float* __restrict__ protO) {
    int wave = (blockIdx.x * blockDim.x + threadIdx.x) >> 6;
    int lane = threadIdx.x & 63;
    if (wave >= N_PROT) return;
    int deg = cnt[wave];
    int m = deg < CAP ? deg : CAP;
    float acc[OUT_D] = {0.f, 0.f, 0.f, 0.f, 0.f};
    const int* br = &bucket[wave * CAP];
    for (int j = lane; j < m; j += 64) {
        const float* p = &P_A[br[j] * OUT_D];
#pragma unroll
        for (int o = 0; o < OUT_D; ++o) acc[o] += p[o];
    }
    if (deg > CAP) {   // exact tail via overflow list
        int nv = *novf; if (nv > OVF_MAX) nv = OVF_MAX;
        for (int j = lane; j < nv; j += 64) {
            if (ovf[2 * j] == wave) {
                const float* p = &P_A[ovf[2 * j + 1] * OUT_D];
#pragma unroll
                for (int o = 0; o < OUT_D; ++o) acc[o] += p[o];
            }
        }
    }
#pragma unroll
    for (int o = 0; o < OUT_D; ++o) {
        float v = acc[o];
        for (int off = 32; off; off >>= 1) v += __shfl_xor(v, off, 64);
        acc[o] = v;
    }
    if (lane < OUT_D)
        protO[wave * OUT_D + lane] += acc[lane] / fmaxf((float)deg, 1.f);
}

// =========================================================================
// D4: final gather-add
// =========================================================================
__global__ void k_final(const int* __restrict__ lbl_src, const int* __restrict__ lbl_dst,
                        const float* __restrict__ drugO, const float* __restrict__ protO,
                        const float* __restrict__ b_lin, float* __restrict__ out) {
    int l = blockIdx.x * blockDim.x + threadIdx.x;
    if (l >= N_LBL) return;
    int s = lbl_src[l], d = lbl_dst[l];
    const float* dr = &drugO[s * OUT_D];
    const float* pr = &protO[d * OUT_D];
    float* op = &out[(size_t)l * OUT_D];
    op[0] = dr[0] + pr[0] + b_lin[0];
    op[1] = dr[1] + pr[1] + b_lin[1];
    op[2] = dr[2] + pr[2] + b_lin[2];
    op[3] = dr[3] + pr[3] + b_lin[3];
    op[4] = dr[4] + pr[4] + b_lin[4];
}

extern "C" void kernel_launch(void* const* d_in, const int* in_sizes, int n_in,
                              void* d_out, int out_size, void* d_ws, size_t ws_size,
                              hipStream_t stream) {
    const float* x_drug   = (const float*)d_in[0];
    const float* x_prot   = (const float*)d_in[1];
    const int*   edge_src = (const int*)d_in[2];
    const int*   edge_dst = (const int*)d_in[3];
    const int*   lbl_src  = (const int*)d_in[4];
    const int*   lbl_dst  = (const int*)d_in[5];
    const float* W_l      = (const float*)d_in[6];
    const float* b_l      = (const float*)d_in[7];
    const float* W_r      = (const float*)d_in[8];
    const float* W_lin    = (const float*)d_in[9];
    const float* b_lin    = (const float*)d_in[10];
    float* out = (float*)d_out;

    // workspace layout; [0, 63648) zeroed by the single memset
    char* ws = (char*)d_ws;
    int*   cnt    = (int*)  (ws + 0);          //  32000 B (8000)     [zeroed]
    int*   novf   = (int*)  (ws + 32000);      //     16 B           [zeroed]
    float* A      = (float*)(ws + 32016);      //   6000 B (5x300)   [zeroed]
    float* B      = (float*)(ws + 38016);      //  25600 B (5x1280)  [zeroed]
    float* c      = (float*)(ws + 63616);      //     20 B           [zeroed]
    float* P_A    = (float*)(ws + 64000);      // 400000 B
    float* drugO  = (float*)(ws + 464000);     // 400000 B
    float* protO  = (float*)(ws + 864000);     // 160000 B
    int*   bucket = (int*)  (ws + 1024000);    // 3072000 B (8000 x 96)
    int*   ovf    = (int*)  (ws + 4096000);    // 524288 B (65536 pairs)
    // total: 4,620,288 B

    hipMemsetAsync(ws, 0, 63648, stream);
    k_fold<<<248, 256, 0, stream>>>(W_l, W_r, W_lin, b_l, A, B, c);
    k_mid<<<3250, 256, 0, stream>>>(
        x_drug, x_prot, edge_src, edge_dst, A, B, c, W_lin,
        cnt, novf, bucket, ovf, P_A, drugO, protO);
    k_gather<<<(N_PROT * 64) / 256, 256, 0, stream>>>(cnt, novf, bucket, ovf, P_A, protO);
    k_final<<<(N_LBL + 255) / 256, 256, 0, stream>>>(lbl_src, lbl_dst, drugO, protO, b_lin, out);
}